// Round 1
// baseline (583.432 us; speedup 1.0000x reference)
//
#include <hip/hip_runtime.h>
#include <math.h>

#define V 100000
#define D 128
#define A 64
#define LVLS 3
#define NN 20000
#define KK 16

// proj[dst] = W[src] @ Wsub (128x64) + bias
// src = idx ? idx[j] : j ; dst = dst_from_idx ? src : j
__global__ __launch_bounds__(256)
void proj_kernel(const float* __restrict__ W, const float* __restrict__ Wsub,
                 const float* __restrict__ bias, const int* __restrict__ idx,
                 int dst_from_idx, int nrows, float* __restrict__ outp) {
    __shared__ float sW[D * A];   // 32 KB
    for (int i = threadIdx.x; i < D * A; i += 256) sW[i] = Wsub[i];
    __syncthreads();
    int lane = threadIdx.x & 63, wave = threadIdx.x >> 6;
    float b = bias ? bias[lane] : 0.f;
    int j0 = blockIdx.x * 32 + wave * 8;   // 32 rows/block, 8 per wave
    for (int jj = 0; jj < 8; ++jj) {
        int j = j0 + jj;
        if (j >= nrows) break;
        int src = idx ? idx[j] : j;
        int dst = dst_from_idx ? src : j;
        const float* r = W + (size_t)src * D;
        float acc = b;
#pragma unroll
        for (int d = 0; d < D; d += 4) {
            float4 rv = *(const float4*)(r + d);   // wave-uniform broadcast load
            acc += rv.x * sW[(d + 0) * A + lane];
            acc += rv.y * sW[(d + 1) * A + lane];
            acc += rv.z * sW[(d + 2) * A + lane];
            acc += rv.w * sW[(d + 3) * A + lane];
        }
        outp[(size_t)dst * A + lane] = acc;
    }
}

// One block (256 thr) per node n: score K neighbors, double-softmax, weighted sum.
__global__ __launch_bounds__(256)
void attn_kernel(const float* __restrict__ Wc, const float* __restrict__ proj,
                 const float* __restrict__ nodeproj, const int* __restrict__ neigh,
                 const float* __restrict__ maskp, const float* __restrict__ weightp,
                 const float* __restrict__ v_att, float* __restrict__ tmp) {
    int n = blockIdx.x;
    int lane = threadIdx.x & 63, wave = threadIdx.x >> 6;
    __shared__ float np_s[A];
    __shared__ float pre_s[KK], w_s[KK], att_s[KK];
    __shared__ int nb_s[KK];
    __shared__ float red[256];
    if (threadIdx.x < A) np_s[threadIdx.x] = nodeproj[(size_t)n * A + threadIdx.x];
    if (threadIdx.x < KK) {
        nb_s[threadIdx.x] = neigh[n * KK + threadIdx.x];
        w_s[threadIdx.x] = weightp[n * KK + threadIdx.x];
    }
    __syncthreads();
    float va = v_att[lane];
#pragma unroll
    for (int kk = 0; kk < 4; ++kk) {
        int k = wave * 4 + kk;
        int nb = nb_s[k];
        float x = np_s[lane] + proj[(size_t)nb * A + lane];
        x = x > 0.f ? x : 0.01f * x;           // leaky_relu(0.01)
        float p = x * va;
#pragma unroll
        for (int off = 32; off >= 1; off >>= 1) p += __shfl_xor(p, off);
        if (lane == 0) pre_s[k] = p + maskp[n * KK + k];
    }
    __syncthreads();
    if (threadIdx.x < KK) {
        float mp = -1e30f, mw = -1e30f;
        for (int k = 0; k < KK; ++k) { mp = fmaxf(mp, pre_s[k]); mw = fmaxf(mw, w_s[k]); }
        float sp = 0.f, sw = 0.f;
        for (int k = 0; k < KK; ++k) { sp += expf(pre_s[k] - mp); sw += expf(w_s[k] - mw); }
        int k = threadIdx.x;
        att_s[k] = (expf(pre_s[k] - mp) / sp) * (expf(w_s[k] - mw) / sw);
    }
    __syncthreads();
    int d = threadIdx.x & 127, h = threadIdx.x >> 7;
    float acc = 0.f;
#pragma unroll
    for (int kk = 0; kk < 8; ++kk) {
        int k = h * 8 + kk;
        acc += Wc[(size_t)nb_s[k] * D + d] * att_s[k];
    }
    red[threadIdx.x] = acc;
    __syncthreads();
    if (threadIdx.x < D)
        tmp[(size_t)n * D + threadIdx.x] = red[threadIdx.x] + red[threadIdx.x + 128];
}

__global__ void amax_kernel(const int* __restrict__ nodes_l, int* __restrict__ claim, int n) {
    int i = blockIdx.x * 256 + threadIdx.x;
    if (i < n) atomicMax(&claim[nodes_l[i]], i);
}

// last-occurrence-wins scatter (matches numpy fancy-assign semantics)
__global__ void scatter_kernel(const int* __restrict__ nodes_l, const int* __restrict__ claim,
                               const float* __restrict__ tmp, float* __restrict__ out, int n) {
    int tid = blockIdx.x * 256 + threadIdx.x;
    int nn = tid >> 7, d = tid & 127;
    if (nn < n) {
        int v = nodes_l[nn];
        if (claim[v] == nn) out[(size_t)v * D + d] = tmp[(size_t)nn * D + d];
    }
}

extern "C" void kernel_launch(void* const* d_in, const int* in_sizes, int n_in,
                              void* d_out, int out_size, void* d_ws, size_t ws_size,
                              hipStream_t stream) {
    const float* Leaf    = (const float*)d_in[0];
    const int*   nodes   = (const int*)d_in[1];
    const int*   neigh   = (const int*)d_in[2];
    const float* masks   = (const float*)d_in[3];
    const float* weights = (const float*)d_in[4];
    const float* Watt    = (const float*)d_in[5];
    const float* batt    = (const float*)d_in[6];
    const float* vatt    = (const float*)d_in[7];
    float* out = (float*)d_out;

    char* ws = (char*)d_ws;
    float* proj     = (float*)ws;                                   // V*A      = 25.6 MB
    float* nodeproj = (float*)(ws + (size_t)V * A * 4);             // L*N*A    = 15.36 MB
    float* tmp      = (float*)(ws + (size_t)V * A * 4 + (size_t)LVLS * NN * A * 4);  // N*D = 10.24 MB
    int*   claim    = (int*)(ws + (size_t)V * A * 4 + (size_t)LVLS * NN * A * 4
                                + (size_t)NN * D * 4);              // V*4      = 0.4 MB

    // W_tmp := Leaf_emb
    hipMemcpyAsync(out, Leaf, (size_t)V * D * sizeof(float), hipMemcpyDeviceToDevice, stream);
    // node-half projection for all levels at once (uses ORIGINAL Leaf_emb)
    proj_kernel<<<(LVLS * NN + 31) / 32, 256, 0, stream>>>(Leaf, Watt, batt, nodes, 0, LVLS * NN, nodeproj);
    // neighbor-half projection for all V rows of current W_tmp
    proj_kernel<<<(V + 31) / 32, 256, 0, stream>>>(out, Watt + D * A, nullptr, nullptr, 0, V, proj);

    for (int l = 0; l < LVLS; ++l) {
        const int* nodes_l = nodes + l * NN;
        attn_kernel<<<NN, 256, 0, stream>>>(out, proj, nodeproj + (size_t)l * NN * A,
                                            neigh + (size_t)l * NN * KK,
                                            masks + (size_t)l * NN * KK,
                                            weights + (size_t)l * NN * KK, vatt, tmp);
        hipMemsetAsync(claim, 0xFF, (size_t)V * sizeof(int), stream);   // -1
        amax_kernel<<<(NN + 255) / 256, 256, 0, stream>>>(nodes_l, claim, NN);
        scatter_kernel<<<(NN * D + 255) / 256, 256, 0, stream>>>(nodes_l, claim, tmp, out, NN);
        if (l + 1 < LVLS)  // refresh proj only for rows just rewritten
            proj_kernel<<<(NN + 31) / 32, 256, 0, stream>>>(out, Watt + D * A, nullptr, nodes_l, 1, NN, proj);
    }
}